// Round 8
// baseline (5325.140 us; speedup 1.0000x reference)
//
#include <hip/hip_runtime.h>
#include <math.h>

#define SEQ 4096
#define BATCH 8
#define NIN 1024
#define NH 256
#define NOUT 128
#define M (SEQ*BATCH)   // 32768

typedef _Float16 half8 __attribute__((ext_vector_type(8)));
typedef float f32x4 __attribute__((ext_vector_type(4)));
union U4H8 { uint4 u; half8 h; };
union U1H2 { unsigned u; _Float16 h[2]; };

// ---------------- K1: xp = x @ W_xh + b_i2h  (M x NIN) @ (NIN x NH) ----------------
__global__ __launch_bounds__(256) void k_xproj(const float* __restrict__ x,
                                               const float* __restrict__ Wi2h,
                                               const float* __restrict__ bi2h,
                                               float* __restrict__ xp) {
    __shared__ __align__(16) float At[32][64];
    __shared__ __align__(16) float Bt[32][64];
    int bid = blockIdx.x;
    int bn_blk = bid & 3, bm_blk = bid >> 2;
    int m0 = bm_blk * 64, n0 = bn_blk * 64;
    int tid = threadIdx.x;
    int tx = tid & 15, ty = tid >> 4;
    int lr = tid >> 3;
    int lc = tid & 7;
    int bk = tid >> 4;
    int bn = (tid & 15) * 4;

    float acc[4][4];
    #pragma unroll
    for (int i = 0; i < 4; i++)
        #pragma unroll
        for (int j = 0; j < 4; j++) acc[i][j] = 0.f;

    for (int k0 = 0; k0 < NIN; k0 += 32) {
        float4 a0 = *(const float4*)&x[(size_t)(m0 + lr)      * NIN + k0 + lc * 4];
        float4 a1 = *(const float4*)&x[(size_t)(m0 + lr + 32) * NIN + k0 + lc * 4];
        float4 b0 = *(const float4*)&Wi2h[(size_t)(k0 + bk)      * NH + n0 + bn];
        float4 b1 = *(const float4*)&Wi2h[(size_t)(k0 + bk + 16) * NH + n0 + bn];
        __syncthreads();
        At[lc*4+0][lr] = a0.x; At[lc*4+1][lr] = a0.y; At[lc*4+2][lr] = a0.z; At[lc*4+3][lr] = a0.w;
        At[lc*4+0][lr+32] = a1.x; At[lc*4+1][lr+32] = a1.y; At[lc*4+2][lr+32] = a1.z; At[lc*4+3][lr+32] = a1.w;
        *(float4*)&Bt[bk][bn]      = b0;
        *(float4*)&Bt[bk+16][bn]   = b1;
        __syncthreads();
        #pragma unroll
        for (int kk = 0; kk < 32; kk++) {
            float4 av = *(const float4*)&At[kk][ty*4];
            float4 bv = *(const float4*)&Bt[kk][tx*4];
            float a[4] = {av.x, av.y, av.z, av.w};
            float b[4] = {bv.x, bv.y, bv.z, bv.w};
            #pragma unroll
            for (int i = 0; i < 4; i++)
                #pragma unroll
                for (int j = 0; j < 4; j++)
                    acc[i][j] = fmaf(a[i], b[j], acc[i][j]);
        }
    }
    float4 bb = *(const float4*)&bi2h[n0 + tx*4];
    float bias[4] = {bb.x, bb.y, bb.z, bb.w};
    #pragma unroll
    for (int i = 0; i < 4; i++) {
        float4 v = make_float4(acc[i][0] + bias[0], acc[i][1] + bias[1],
                               acc[i][2] + bias[2], acc[i][3] + bias[3]);
        *(float4*)&xp[(size_t)(m0 + ty*4 + i) * NH + n0 + tx*4] = v;
    }
}

// ---------------- K2: MFMA scan — ONE block (256 thr, 4 waves) does all 8 batches ---
// D[j][b] = sum_k W_hh[k][j] * h[b][k]  via mfma_f32_16x16x32_f16:
//   A = W~ tiles (M=j), preloaded as fragments (128 u32/lane) — MFMA reads
//   VGPR/AGPR natively, so the round-5/6 per-use copy tax vanishes.
//   B = h fragments from LDS f16 [k>>3][b(16, 8 pad)][k&7]; b128 reads conflict-free.
//   C seeded with xp (bias add free). D layout (m89): col=lane&15=b,
//   row=(lane>>4)*4+q=j_local. A/B use the SAME (g,e)->k map, so the HW's
//   intra-fragment k permutation cancels (sum over k is permutation-invariant).
// Wave w owns j-tiles w*4..w*4+3. Per step: 8 ds_read_b128 + 32 MFMA + tanh
// epilogue + b64 LDS write of new h (f16) + predicated f32 hs/xp global traffic.
// Double-buffered h; ONE lgkm-only barrier per step (global ops stay in flight).
__global__ __launch_bounds__(256) __attribute__((amdgpu_waves_per_eu(1, 1)))
void k_scan(const float* __restrict__ Wi2h,
            const float* __restrict__ h0,
            const float* __restrict__ xp,
            float* __restrict__ hs) {
    __shared__ __align__(16) unsigned hbuf[2][2048];   // [buf][(kgrp*16+b)*4 + c], 8KB each
    int tid = threadIdx.x;
    int w = tid >> 6;          // wave 0..3
    int l = tid & 63;
    int bcol = l & 15;         // A-row j_local / B-col b / D-col b
    int g = l >> 4;            // k-subgroup / D-row-group

    // ---- preload W~ A-fragments: wa[m][kt], slot e <-> k = kt*32 + g*8 + e ----
    uint4 wa[4][8];
    #pragma unroll
    for (int m = 0; m < 4; m++) {
        #pragma unroll
        for (int kt = 0; kt < 8; kt++) {
            int j = (w*4 + m)*16 + bcol;
            int kbase = kt*32 + g*8;
            U4H8 f;
            #pragma unroll
            for (int e = 0; e < 8; e++)
                f.h[e] = (_Float16)Wi2h[(size_t)(NIN + kbase + e)*NH + j];
            wa[m][kt] = f.u;
        }
    }
    #pragma unroll
    for (int m = 0; m < 4; m++)
        #pragma unroll
        for (int kt = 0; kt < 8; kt++)
            asm volatile("" : "+v"(wa[m][kt].x), "+v"(wa[m][kt].y),
                             "+v"(wa[m][kt].z), "+v"(wa[m][kt].w));

    // ---- init h buffer 0 from h0 (pad rows b>=8 zero) ----
    for (int i = tid; i < 2048; i += 256) {
        int c = i & 3, line = i >> 2, b = line & 15, kgrp = line >> 4;
        int k = kgrp*8 + c*2;
        U1H2 pr; pr.u = 0;
        if (b < 8) {
            pr.h[0] = (_Float16)h0[b*NH + k];
            pr.h[1] = (_Float16)h0[b*NH + k + 1];
        }
        hbuf[0][i] = pr.u;
    }
    __syncthreads();

    // ---- prefetch xp for t=0 ----
    float4 xq[4];
    #pragma unroll
    for (int m = 0; m < 4; m++) {
        xq[m] = make_float4(0.f, 0.f, 0.f, 0.f);
        if (bcol < 8) {
            int j0 = (w*4 + m)*16 + g*4;
            xq[m] = *(const float4*)&xp[(size_t)(0*BATCH + bcol)*NH + j0];
        }
    }

    for (int t = 0; t < SEQ; t++) {
        int cur = t & 1, nxt = cur ^ 1;

        // B-fragments of h (slot e <-> k = (kt*4+g)*8 + e — same map as A)
        uint4 hbv[8];
        #pragma unroll
        for (int kt = 0; kt < 8; kt++)
            hbv[kt] = *(const uint4*)&hbuf[cur][((kt*4 + g)*16 + bcol)*4];

        // prefetch next xp (stays in flight across the barrier)
        float4 xn[4];
        #pragma unroll
        for (int m = 0; m < 4; m++) {
            xn[m] = make_float4(0.f, 0.f, 0.f, 0.f);
            if (t + 1 < SEQ && bcol < 8) {
                int j0 = (w*4 + m)*16 + g*4;
                xn[m] = *(const float4*)&xp[((size_t)(t+1)*BATCH + bcol)*NH + j0];
            }
        }

        // MFMA: acc[m] = xp-seed + sum_kt A(W~)*B(h)
        f32x4 acc[4];
        #pragma unroll
        for (int m = 0; m < 4; m++) {
            acc[m][0] = xq[m].x; acc[m][1] = xq[m].y;
            acc[m][2] = xq[m].z; acc[m][3] = xq[m].w;
        }
        #pragma unroll
        for (int kt = 0; kt < 8; kt++) {
            U4H8 hb; hb.u = hbv[kt];
            #pragma unroll
            for (int m = 0; m < 4; m++) {
                U4H8 af; af.u = wa[m][kt];
                acc[m] = __builtin_amdgcn_mfma_f32_16x16x32_f16(af.h, hb.h, acc[m], 0, 0, 0);
            }
        }

        // epilogue: tanh, write f16 h to LDS (next buf), f32 hs to global
        #pragma unroll
        for (int m = 0; m < 4; m++) {
            float hn[4];
            #pragma unroll
            for (int q = 0; q < 4; q++) {
                float s = acc[m][q];
                float arg = s * 2.88539004f;       // 2*log2(e)*s
                float z;   asm("v_exp_f32 %0, %1" : "=v"(z)   : "v"(arg));
                float den = z + 1.0f;
                float inv; asm("v_rcp_f32 %0, %1" : "=v"(inv) : "v"(den));
                hn[q] = (z - 1.0f) * inv;          // tanh(s)
            }
            unsigned p01, p23;
            asm("v_cvt_pkrtz_f16_f32 %0, %1, %2" : "=v"(p01) : "v"(hn[0]), "v"(hn[1]));
            asm("v_cvt_pkrtz_f16_f32 %0, %1, %2" : "=v"(p23) : "v"(hn[2]), "v"(hn[3]));
            int j0 = (w*4 + m)*16 + g*4;
            int line = (j0 >> 3)*16 + bcol;
            *(uint2*)&hbuf[nxt][line*4 + ((j0 & 7) >> 1)] = make_uint2(p01, p23);
            if (bcol < 8)
                *(float4*)&hs[((size_t)t*BATCH + bcol)*NH + j0] =
                    make_float4(hn[0], hn[1], hn[2], hn[3]);
            xq[m] = xn[m];
        }

        // lgkm-only barrier: LDS writes visible; global load/store stay in flight
        asm volatile("s_waitcnt lgkmcnt(0)" ::: "memory");
        __builtin_amdgcn_s_barrier();
        asm volatile("" ::: "memory");
    }
}

// ---------------- K3: out = hs @ W_h2o + b_h2o ----------------
__global__ __launch_bounds__(256) void k_out(const float* __restrict__ hs,
                                             const float* __restrict__ Wh2o,
                                             const float* __restrict__ bh2o,
                                             float* __restrict__ out) {
    __shared__ float Wl[NH][64];
    __shared__ float Hl[8][NH];
    int bid = blockIdx.x;
    int half = bid & 1;
    int rt = bid >> 1;
    int tid = threadIdx.x;

    for (int i = tid; i < NH*64; i += 256) {
        int k = i >> 6, o = i & 63;
        Wl[k][o] = Wh2o[(size_t)k*NOUT + half*64 + o];
    }
    int o = tid & 63, g = tid >> 6;
    float bias = bh2o[half*64 + o];

    for (int tile = 0; tile < 16; tile++) {
        int r0 = rt*128 + tile*8;
        __syncthreads();
        for (int i = tid; i < 8*NH; i += 256)
            Hl[i >> 8][i & 255] = hs[(size_t)r0*NH + i];
        __syncthreads();
        float a0 = 0.f, a1 = 0.f;
        int r = g * 2;
        #pragma unroll 8
        for (int k = 0; k < NH; k++) {
            float wv = Wl[k][o];
            a0 = fmaf(Hl[r][k],   wv, a0);
            a1 = fmaf(Hl[r+1][k], wv, a1);
        }
        out[(size_t)(r0 + r)     * NOUT + half*64 + o] = a0 + bias;
        out[(size_t)(r0 + r + 1) * NOUT + half*64 + o] = a1 + bias;
    }
}

extern "C" void kernel_launch(void* const* d_in, const int* in_sizes, int n_in,
                              void* d_out, int out_size, void* d_ws, size_t ws_size,
                              hipStream_t stream) {
    const float* x    = (const float*)d_in[0];
    const float* h0   = (const float*)d_in[1];
    const float* Wi2h = (const float*)d_in[2];
    const float* bi2h = (const float*)d_in[3];
    const float* Wh2o = (const float*)d_in[4];
    const float* bh2o = (const float*)d_in[5];
    float* out = (float*)d_out;

    float* xp = (float*)d_ws;                     // M*NH f32 = 32 MB
    float* hs = xp + (size_t)M * NH;              // M*NH f32 = 32 MB

    k_xproj<<<dim3(2048), dim3(256), 0, stream>>>(x, Wi2h, bi2h, xp);
    k_scan <<<dim3(1),    dim3(256), 0, stream>>>(Wi2h, h0, xp, hs);
    k_out  <<<dim3(512),  dim3(256), 0, stream>>>(hs, Wh2o, bh2o, out);
}

// Round 9
// 2829.824 us; speedup vs baseline: 1.8818x; 1.8818x over previous
//
#include <hip/hip_runtime.h>
#include <math.h>

#define SEQ 4096
#define BATCH 8
#define NIN 1024
#define NH 256
#define NOUT 128
#define M (SEQ*BATCH)   // 32768

// ---------------- K1: xp = x @ W_xh + b_i2h  (M x NIN) @ (NIN x NH) ----------------
__global__ __launch_bounds__(256) void k_xproj(const float* __restrict__ x,
                                               const float* __restrict__ Wi2h,
                                               const float* __restrict__ bi2h,
                                               float* __restrict__ xp) {
    __shared__ __align__(16) float At[32][64];
    __shared__ __align__(16) float Bt[32][64];
    int bid = blockIdx.x;
    int bn_blk = bid & 3, bm_blk = bid >> 2;
    int m0 = bm_blk * 64, n0 = bn_blk * 64;
    int tid = threadIdx.x;
    int tx = tid & 15, ty = tid >> 4;
    int lr = tid >> 3;
    int lc = tid & 7;
    int bk = tid >> 4;
    int bn = (tid & 15) * 4;

    float acc[4][4];
    #pragma unroll
    for (int i = 0; i < 4; i++)
        #pragma unroll
        for (int j = 0; j < 4; j++) acc[i][j] = 0.f;

    for (int k0 = 0; k0 < NIN; k0 += 32) {
        float4 a0 = *(const float4*)&x[(size_t)(m0 + lr)      * NIN + k0 + lc * 4];
        float4 a1 = *(const float4*)&x[(size_t)(m0 + lr + 32) * NIN + k0 + lc * 4];
        float4 b0 = *(const float4*)&Wi2h[(size_t)(k0 + bk)      * NH + n0 + bn];
        float4 b1 = *(const float4*)&Wi2h[(size_t)(k0 + bk + 16) * NH + n0 + bn];
        __syncthreads();
        At[lc*4+0][lr] = a0.x; At[lc*4+1][lr] = a0.y; At[lc*4+2][lr] = a0.z; At[lc*4+3][lr] = a0.w;
        At[lc*4+0][lr+32] = a1.x; At[lc*4+1][lr+32] = a1.y; At[lc*4+2][lr+32] = a1.z; At[lc*4+3][lr+32] = a1.w;
        *(float4*)&Bt[bk][bn]      = b0;
        *(float4*)&Bt[bk+16][bn]   = b1;
        __syncthreads();
        #pragma unroll
        for (int kk = 0; kk < 32; kk++) {
            float4 av = *(const float4*)&At[kk][ty*4];
            float4 bv = *(const float4*)&Bt[kk][tx*4];
            float a[4] = {av.x, av.y, av.z, av.w};
            float b[4] = {bv.x, bv.y, bv.z, bv.w};
            #pragma unroll
            for (int i = 0; i < 4; i++)
                #pragma unroll
                for (int j = 0; j < 4; j++)
                    acc[i][j] = fmaf(a[i], b[j], acc[i][j]);
        }
    }
    float4 bb = *(const float4*)&bi2h[n0 + tx*4];
    float bias[4] = {bb.x, bb.y, bb.z, bb.w};
    #pragma unroll
    for (int i = 0; i < 4; i++) {
        float4 v = make_float4(acc[i][0] + bias[0], acc[i][1] + bias[1],
                               acc[i][2] + bias[2], acc[i][3] + bias[3]);
        *(float4*)&xp[(size_t)(m0 + ty*4 + i) * NH + n0 + tx*4] = v;
    }
}

// ---------------- K2: sequential scan, one block per batch (round-6 base) ----------
// 512 threads = 8 waves. Thread (cb = tid>>3, kb = tid&7) owns 4 cols x 32 k.
// CHANGE vs round 6: xp prefetch pipeline deepened 1 -> 4 steps. Round-7 A/B
// showed halved FMA count + halved weight regs changed nothing -> the floor is
// the serial xp load latency (issued top of step t, consumed end of step t,
// and its waitcnt also drains the earlier hs store). 4-deep ring xv[0..3]
// (fully unrolled -> static indices) gives ~3.5 steps (~4500 cyc) of slack.
// hbuf parity becomes static (i&1). One lgkm-only barrier per step.
__global__ __launch_bounds__(512) __attribute__((amdgpu_waves_per_eu(2, 2)))
void k_scan(const float* __restrict__ Wi2h,
            const float* __restrict__ h0,
            const float* __restrict__ xp,
            float* __restrict__ hs) {
    __shared__ __align__(16) float hbuf[2][NH];
    int b = blockIdx.x;
    int tid = threadIdx.x;
    int cb = tid >> 3;            // 0..63  -> columns 4cb..4cb+3
    int kb = tid & 7;             // 0..7   -> k rows 32kb..32kb+31
    int b0 = kb & 1, b1 = (kb >> 1) & 1;
    int colf = 4*cb + (b0 << 1) + b1;    // final owned column after reduce

    // Weight registers: w4[c][j] = W_hh[32kb + 4*((j+kb)&7) + e][4cb+c]
    float4 w4[4][8];
    #pragma unroll
    for (int c = 0; c < 4; c++) {
        #pragma unroll
        for (int j = 0; j < 8; j++) {
            int kk = 32*kb + 4*((j + kb) & 7);
            const float* base = &Wi2h[(size_t)(NIN + kk) * NH + 4*cb + c];
            w4[c][j].x = base[0*NH];
            w4[c][j].y = base[1*NH];
            w4[c][j].z = base[2*NH];
            w4[c][j].w = base[3*NH];
        }
    }
    // Launder: opaque asm results -> cannot be rematerialized from global.
    #pragma unroll
    for (int c = 0; c < 4; c++)
        #pragma unroll
        for (int j = 0; j < 8; j++)
            asm volatile("" : "+v"(w4[c][j].x), "+v"(w4[c][j].y),
                             "+v"(w4[c][j].z), "+v"(w4[c][j].w));

    if (tid < NH) hbuf[0][tid] = h0[b*NH + tid];

    // 4-deep xp prefetch ring (fully unrolled -> promoted to scalars)
    float xv[4];
    #pragma unroll
    for (int i = 0; i < 4; i++)
        xv[i] = xp[(size_t)(i*BATCH + b) * NH + colf];
    __syncthreads();

    for (int T = 0; T < SEQ; T += 4) {
        #pragma unroll
        for (int i = 0; i < 4; i++) {
            int t = T + i;
            const float* rb = &hbuf[i & 1][32 * kb];

            float4 hv[8];
            #pragma unroll
            for (int j = 0; j < 8; j++)
                hv[j] = *(const float4*)&rb[4 * ((j + kb) & 7)];

            float a0 = 0.f, a1 = 0.f, a2 = 0.f, a3 = 0.f;
            #pragma unroll
            for (int j = 0; j < 8; j++) {
                a0 = fmaf(hv[j].x, w4[0][j].x, a0); a0 = fmaf(hv[j].y, w4[0][j].y, a0);
                a0 = fmaf(hv[j].z, w4[0][j].z, a0); a0 = fmaf(hv[j].w, w4[0][j].w, a0);
                a1 = fmaf(hv[j].x, w4[1][j].x, a1); a1 = fmaf(hv[j].y, w4[1][j].y, a1);
                a1 = fmaf(hv[j].z, w4[1][j].z, a1); a1 = fmaf(hv[j].w, w4[1][j].w, a1);
                a2 = fmaf(hv[j].x, w4[2][j].x, a2); a2 = fmaf(hv[j].y, w4[2][j].y, a2);
                a2 = fmaf(hv[j].z, w4[2][j].z, a2); a2 = fmaf(hv[j].w, w4[2][j].w, a2);
                a3 = fmaf(hv[j].x, w4[3][j].x, a3); a3 = fmaf(hv[j].y, w4[3][j].y, a3);
                a3 = fmaf(hv[j].z, w4[3][j].z, a3); a3 = fmaf(hv[j].w, w4[3][j].w, a3);
            }

            // select-fold reduction over kb lanes (xor 1, 2, 4) — 4 shfls
            bool s0 = (kb & 1) != 0, s1 = (kb & 2) != 0;
            float k0v = s0 ? a2 : a0, k1v = s0 ? a3 : a1;
            float d0  = s0 ? a0 : a2, d1  = s0 ? a1 : a3;
            k0v += __shfl_xor(d0, 1, 64);
            k1v += __shfl_xor(d1, 1, 64);
            float ke = s1 ? k1v : k0v;
            float de = s1 ? k0v : k1v;
            ke += __shfl_xor(de, 2, 64);
            ke += __shfl_xor(ke, 4, 64);

            float s = ke + xv[i];
            // tanh via (z-1)/(z+1), z = exp2(2*log2(e)*s)
            float arg = s * 2.88539004f;
            float z;
            asm("v_exp_f32 %0, %1" : "=v"(z) : "v"(arg));
            float inv;
            float den = z + 1.0f;
            asm("v_rcp_f32 %0, %1" : "=v"(inv) : "v"(den));
            float hn = (z - 1.0f) * inv;

            if ((kb & 4) == 0) hbuf[(i + 1) & 1][colf] = hn;               // LDS for next step
            else               hs[(size_t)(t*BATCH + b) * NH + colf] = hn; // global, in flight

            if (t + 4 < SEQ)
                xv[i] = xp[(size_t)((t+4)*BATCH + b) * NH + colf];         // refill ring slot

            asm volatile("s_waitcnt lgkmcnt(0)" ::: "memory");
            __builtin_amdgcn_s_barrier();
            asm volatile("" ::: "memory");
        }
    }
}

// ---------------- K3: out = hs @ W_h2o + b_h2o ----------------
__global__ __launch_bounds__(256) void k_out(const float* __restrict__ hs,
                                             const float* __restrict__ Wh2o,
                                             const float* __restrict__ bh2o,
                                             float* __restrict__ out) {
    __shared__ float Wl[NH][64];
    __shared__ float Hl[8][NH];
    int bid = blockIdx.x;
    int half = bid & 1;
    int rt = bid >> 1;
    int tid = threadIdx.x;

    for (int i = tid; i < NH*64; i += 256) {
        int k = i >> 6, o = i & 63;
        Wl[k][o] = Wh2o[(size_t)k*NOUT + half*64 + o];
    }
    int o = tid & 63, g = tid >> 6;
    float bias = bh2o[half*64 + o];

    for (int tile = 0; tile < 16; tile++) {
        int r0 = rt*128 + tile*8;
        __syncthreads();
        for (int i = tid; i < 8*NH; i += 256)
            Hl[i >> 8][i & 255] = hs[(size_t)r0*NH + i];
        __syncthreads();
        float a0 = 0.f, a1 = 0.f;
        int r = g * 2;
        #pragma unroll 8
        for (int k = 0; k < NH; k++) {
            float wv = Wl[k][o];
            a0 = fmaf(Hl[r][k],   wv, a0);
            a1 = fmaf(Hl[r+1][k], wv, a1);
        }
        out[(size_t)(r0 + r)     * NOUT + half*64 + o] = a0 + bias;
        out[(size_t)(r0 + r + 1) * NOUT + half*64 + o] = a1 + bias;
    }
}

extern "C" void kernel_launch(void* const* d_in, const int* in_sizes, int n_in,
                              void* d_out, int out_size, void* d_ws, size_t ws_size,
                              hipStream_t stream) {
    const float* x    = (const float*)d_in[0];
    const float* h0   = (const float*)d_in[1];
    const float* Wi2h = (const float*)d_in[2];
    const float* bi2h = (const float*)d_in[3];
    const float* Wh2o = (const float*)d_in[4];
    const float* bh2o = (const float*)d_in[5];
    float* out = (float*)d_out;

    float* xp = (float*)d_ws;                     // M*NH f32 = 32 MB
    float* hs = xp + (size_t)M * NH;              // M*NH f32 = 32 MB

    k_xproj<<<dim3(2048), dim3(256), 0, stream>>>(x, Wi2h, bi2h, xp);
    k_scan <<<dim3(BATCH), dim3(512), 0, stream>>>(Wi2h, h0, xp, hs);
    k_out  <<<dim3(512), dim3(256), 0, stream>>>(hs, Wh2o, bh2o, out);
}